// Round 1
// baseline (144.618 us; speedup 1.0000x reference)
//
#include <hip/hip_runtime.h>

typedef __attribute__((ext_vector_type(8))) short bf16x8;
typedef __attribute__((ext_vector_type(4))) float f32x4;

__device__ __forceinline__ unsigned short f2bf(float f) {
  unsigned u = __builtin_bit_cast(unsigned, f);
  u += 0x7FFFu + ((u >> 16) & 1u);           // RNE
  return (unsigned short)(u >> 16);
}
__device__ __forceinline__ float bf2f(unsigned short h) {
  unsigned u = ((unsigned)h) << 16;
  return __builtin_bit_cast(float, u);
}

#define MFMA16(a, b, c) __builtin_amdgcn_mfma_f32_16x16x32_bf16(a, b, c, 0, 0, 0)

#define LR 72      // row stride (bf16) for 64-col LDS tiles (+8 pad: rows 16B-aligned, banks rotate)
#define FFR 136    // row stride for the 128-col FF1 tile

// LDS layout (ushort offsets); aliasing by liveness:
//  H(LN1 out) -> P(softmax) -> H2(LN2 out)      @ OFF_H
//  Q,K (attention)          -> FF1 (MLP hidden) @ OFF_Q
//  V^T (attention)          -> X2 (residual 1)  @ OFF_VT
#define OFF_H   0
#define OFF_Q   4608
#define OFF_K   9216
#define OFF_VT  13824
#define OFF_AT  18432
#define LDS_TOT 23040   // 46,080 B -> 3 blocks/CU

// ---- weight prep: repack all weights into MFMA-B-fragment order (bf16) ----
// chunk = 1 KB = one 32x16 B-tile: elem[l*8+jj] = W[32*ks+8*(l>>4)+jj][16*ni+(l&15)]
// chunks: [0,8)=WQ [8,16)=WK [16,24)=WV [24,32)=PROJ [32,64)=FC1 [64,96)=FC2
__global__ void prep_weights(const float* __restrict__ wq, const float* __restrict__ wk,
                             const float* __restrict__ wv, const float* __restrict__ projw,
                             const float* __restrict__ fc1w, const float* __restrict__ fc2w,
                             unsigned short* __restrict__ ws) {
  int c = blockIdx.x, l = threadIdx.x;
  int g = l >> 4, jl = l & 15;
  int kind, ni, ks;
  if (c < 32)      { kind = c >> 3; int cc = c & 7;  ni = cc >> 1; ks = cc & 1; }
  else if (c < 64) { kind = 4;      int cc = c - 32; ni = cc >> 1; ks = cc & 1; }
  else             { kind = 5;      int cc = c - 64; ni = cc >> 3; ks = cc & 7; }
  unsigned short* dst = ws + c * 512 + l * 8;
  int n = 16 * ni + jl;
  #pragma unroll
  for (int jj = 0; jj < 8; ++jj) {
    int k = 32 * ks + 8 * g + jj;
    float v;
    if (kind == 0)      v = wq[(n >> 3) * 512 + k * 8 + (n & 7)];  // wq[h][c][d], n=h*8+d
    else if (kind == 1) v = wk[(n >> 3) * 512 + k * 8 + (n & 7)];
    else if (kind == 2) v = wv[(n >> 3) * 512 + k * 8 + (n & 7)];
    else if (kind == 3) v = projw[k * 64 + n];
    else if (kind == 4) v = fc1w[k * 256 + n];
    else                v = fc2w[k * 64 + n];
    dst[jj] = f2bf(v);
  }
}

__global__ __launch_bounds__(256) void block_fused(
    const float* __restrict__ x,
    const float* __restrict__ ln1w, const float* __restrict__ ln1b,
    const float* __restrict__ projb,
    const float* __restrict__ ln2w, const float* __restrict__ ln2b,
    const float* __restrict__ fc1b, const float* __restrict__ fc2b,
    const unsigned short* __restrict__ ws, float* __restrict__ out) {
  __shared__ __attribute__((aligned(16))) unsigned short lds[LDS_TOT];

  const int tid  = threadIdx.x;
  const int wid  = tid >> 6;     // wave 0..3
  const int lane = tid & 63;
  const int g    = lane >> 4;    // 0..3
  const int jl   = lane & 15;
  const size_t b = blockIdx.x;
  const float* xb = x + b * 4096;

  // ---------- LN1 (4 lanes per row) ----------
  {
    int row = tid >> 2, q = tid & 3;
    const float* xr = xb + row * 64 + q * 16;
    float v[16], s = 0.f, ss = 0.f;
    #pragma unroll
    for (int i = 0; i < 16; ++i) { float t = xr[i]; v[i] = t; s += t; ss += t * t; }
    s  += __shfl_xor(s, 1, 64);  s  += __shfl_xor(s, 2, 64);
    ss += __shfl_xor(ss, 1, 64); ss += __shfl_xor(ss, 2, 64);
    float mean = s * 0.015625f;
    float rstd = rsqrtf(ss * 0.015625f - mean * mean + 1e-5f);
    unsigned short* hr = lds + OFF_H + row * LR + q * 16;
    #pragma unroll
    for (int i = 0; i < 16; ++i) {
      int cc = q * 16 + i;
      hr[i] = f2bf((v[i] - mean) * rstd * ln1w[cc] + ln1b[cc]);
    }
  }
  __syncthreads();

  // ---------- QKV: wave w computes 16-col n-tile w of each of Q,K,V ----------
  #pragma unroll
  for (int t = 0; t < 3; ++t) {
    const unsigned short* wb = ws + t * 4096 + wid * 1024;
    #pragma unroll
    for (int mi = 0; mi < 4; ++mi) {
      f32x4 acc = (f32x4){0.f, 0.f, 0.f, 0.f};
      #pragma unroll
      for (int ks = 0; ks < 2; ++ks) {
        bf16x8 a  = *(const bf16x8*)(lds + OFF_H + (16 * mi + jl) * LR + 8 * g + 32 * ks);
        bf16x8 bb = *(const bf16x8*)(wb + ks * 512 + lane * 8);
        acc = MFMA16(a, bb, acc);
      }
      #pragma unroll
      for (int r = 0; r < 4; ++r) {
        int i = 16 * mi + 4 * g + r;
        int j = 16 * wid + jl;
        unsigned short hv = f2bf(acc[r]);
        if (t == 0)      lds[OFF_Q + i * LR + j] = hv;
        else if (t == 1) lds[OFF_K + i * LR + j] = hv;
        else             lds[OFF_VT + j * LR + i] = hv;   // V transposed
      }
    }
  }
  __syncthreads();

  // ---------- attention: wave w owns score rows 16w..16w+15; P is wave-private -> no barriers ----------
  {
    const bf16x8 z8 = {0, 0, 0, 0, 0, 0, 0, 0};
    const f32x4  zf = {0.f, 0.f, 0.f, 0.f};
    for (int h = 0; h < 8; ++h) {
      // scores S = Q_h @ K_h^T (K-dim 8, padded to 32: only g==0 lanes carry data)
      bf16x8 aq = *(const bf16x8*)(lds + OFF_Q + (16 * wid + jl) * LR + h * 8);
      if (g != 0) aq = z8;
      f32x4 sc[4];
      #pragma unroll
      for (int ni = 0; ni < 4; ++ni) {
        bf16x8 bk = *(const bf16x8*)(lds + OFF_K + (16 * ni + jl) * LR + h * 8);
        if (g != 0) bk = z8;
        sc[ni] = MFMA16(aq, bk, zf);
      }
      // causal softmax over rows 16*wid+4g+r (row lives in 16 lanes sharing g)
      #pragma unroll
      for (int r = 0; r < 4; ++r) {
        int i = 16 * wid + 4 * g + r;
        float sv[4], m = -1e30f;
        #pragma unroll
        for (int ni = 0; ni < 4; ++ni) {
          float vv = sc[ni][r] * 0.125f;                 // C^-0.5 = 1/8
          vv = (16 * ni + jl <= i) ? vv : -1e30f;        // causal mask
          sv[ni] = vv; m = fmaxf(m, vv);
        }
        m = fmaxf(m, __shfl_xor(m, 1, 64)); m = fmaxf(m, __shfl_xor(m, 2, 64));
        m = fmaxf(m, __shfl_xor(m, 4, 64)); m = fmaxf(m, __shfl_xor(m, 8, 64));
        float sum = 0.f;
        #pragma unroll
        for (int ni = 0; ni < 4; ++ni) { float p = __expf(sv[ni] - m); sv[ni] = p; sum += p; }
        sum += __shfl_xor(sum, 1, 64); sum += __shfl_xor(sum, 2, 64);
        sum += __shfl_xor(sum, 4, 64); sum += __shfl_xor(sum, 8, 64);
        float inv = 1.f / sum;
        #pragma unroll
        for (int ni = 0; ni < 4; ++ni)
          lds[OFF_H + i * LR + 16 * ni + jl] = f2bf(sv[ni] * inv);   // P -> H region
      }
      // PV: attn rows 16w.., cols h*8..h*8+7 (N padded to 16: only jl<8 valid)
      f32x4 av = zf;
      #pragma unroll
      for (int ks = 0; ks < 2; ++ks) {
        bf16x8 ap = *(const bf16x8*)(lds + OFF_H + (16 * wid + jl) * LR + 8 * g + 32 * ks);
        bf16x8 bv = z8;
        if (jl < 8)
          bv = *(const bf16x8*)(lds + OFF_VT + (h * 8 + jl) * LR + 8 * g + 32 * ks);
        av = MFMA16(ap, bv, av);
      }
      if (jl < 8) {
        #pragma unroll
        for (int r = 0; r < 4; ++r)
          lds[OFF_AT + (16 * wid + 4 * g + r) * LR + h * 8 + jl] = f2bf(av[r]);
      }
    }
  }
  __syncthreads();

  // ---------- proj + residual: x2 = x + attn@proj_w + proj_b (bf16 into VT region) ----------
  {
    const unsigned short* wb = ws + 12288 + wid * 1024;
    #pragma unroll
    for (int mi = 0; mi < 4; ++mi) {
      f32x4 acc = (f32x4){0.f, 0.f, 0.f, 0.f};
      #pragma unroll
      for (int ks = 0; ks < 2; ++ks) {
        bf16x8 a  = *(const bf16x8*)(lds + OFF_AT + (16 * mi + jl) * LR + 8 * g + 32 * ks);
        bf16x8 bb = *(const bf16x8*)(wb + ks * 512 + lane * 8);
        acc = MFMA16(a, bb, acc);
      }
      int j = 16 * wid + jl;
      float pb = projb[j];
      #pragma unroll
      for (int r = 0; r < 4; ++r) {
        int i = 16 * mi + 4 * g + r;
        lds[OFF_VT + i * LR + j] = f2bf(xb[i * 64 + j] + acc[r] + pb);  // x re-read: L2-hot
      }
    }
  }
  __syncthreads();

  // ---------- LN2 ----------
  {
    int row = tid >> 2, q = tid & 3;
    const unsigned short* xr = lds + OFF_VT + row * LR + q * 16;
    float v[16], s = 0.f, ss = 0.f;
    #pragma unroll
    for (int i = 0; i < 16; ++i) { float t = bf2f(xr[i]); v[i] = t; s += t; ss += t * t; }
    s  += __shfl_xor(s, 1, 64);  s  += __shfl_xor(s, 2, 64);
    ss += __shfl_xor(ss, 1, 64); ss += __shfl_xor(ss, 2, 64);
    float mean = s * 0.015625f;
    float rstd = rsqrtf(ss * 0.015625f - mean * mean + 1e-5f);
    unsigned short* hr = lds + OFF_H + row * LR + q * 16;
    #pragma unroll
    for (int i = 0; i < 16; ++i) {
      int cc = q * 16 + i;
      hr[i] = f2bf((v[i] - mean) * rstd * ln2w[cc] + ln2b[cc]);
    }
  }
  __syncthreads();

  // ---------- FF: hidden 256 split in two halves of 128 (FF1 aliases Q+K region) ----------
  f32x4 acc2[4];
  #pragma unroll
  for (int mi = 0; mi < 4; ++mi) acc2[mi] = (f32x4){0.f, 0.f, 0.f, 0.f};

  for (int half = 0; half < 2; ++half) {
    // fc1: wave w -> 2 n-tiles of this half; relu; bf16 into FF1
    #pragma unroll
    for (int nt = 0; nt < 2; ++nt) {
      int nloc = wid * 2 + nt;          // 0..7 (16-col tiles within the half)
      int ni_g = half * 8 + nloc;       // global n-tile 0..15
      const unsigned short* wb = ws + 16384 + ni_g * 1024;
      #pragma unroll
      for (int mi = 0; mi < 4; ++mi) {
        f32x4 acc = (f32x4){0.f, 0.f, 0.f, 0.f};
        #pragma unroll
        for (int ks = 0; ks < 2; ++ks) {
          bf16x8 a  = *(const bf16x8*)(lds + OFF_H + (16 * mi + jl) * LR + 8 * g + 32 * ks);
          bf16x8 bb = *(const bf16x8*)(wb + ks * 512 + lane * 8);
          acc = MFMA16(a, bb, acc);
        }
        float bias = fc1b[16 * ni_g + jl];
        #pragma unroll
        for (int r = 0; r < 4; ++r) {
          int i = 16 * mi + 4 * g + r;
          lds[OFF_Q + i * FFR + nloc * 16 + jl] = f2bf(fmaxf(acc[r] + bias, 0.f));
        }
      }
    }
    __syncthreads();
    // fc2 partial accumulate over this half's K range (kept in VGPRs across halves)
    const unsigned short* w2 = ws + 32768 + wid * 4096;
    #pragma unroll
    for (int ksl = 0; ksl < 4; ++ksl) {
      int ksg = half * 4 + ksl;
      #pragma unroll
      for (int mi = 0; mi < 4; ++mi) {
        bf16x8 a  = *(const bf16x8*)(lds + OFF_Q + (16 * mi + jl) * FFR + 8 * g + 32 * ksl);
        bf16x8 bb = *(const bf16x8*)(w2 + ksg * 512 + lane * 8);
        acc2[mi] = MFMA16(a, bb, acc2[mi]);
      }
    }
    __syncthreads();
  }

  // ---------- epilogue: out = x2 + ff ----------
  {
    int j = 16 * wid + jl;
    float fb = fc2b[j];
    float* ob = out + b * 4096;
    #pragma unroll
    for (int mi = 0; mi < 4; ++mi) {
      #pragma unroll
      for (int r = 0; r < 4; ++r) {
        int i = 16 * mi + 4 * g + r;
        ob[i * 64 + j] = bf2f(lds[OFF_VT + i * LR + j]) + acc2[mi][r] + fb;
      }
    }
  }
}

extern "C" void kernel_launch(void* const* d_in, const int* in_sizes, int n_in,
                              void* d_out, int out_size, void* d_ws, size_t ws_size,
                              hipStream_t stream) {
  const float* x     = (const float*)d_in[0];
  const float* ln1w  = (const float*)d_in[1];
  const float* ln1b  = (const float*)d_in[2];
  const float* wq    = (const float*)d_in[3];
  const float* wk    = (const float*)d_in[4];
  const float* wvp   = (const float*)d_in[5];
  const float* projw = (const float*)d_in[6];
  const float* projb = (const float*)d_in[7];
  const float* ln2w  = (const float*)d_in[8];
  const float* ln2b  = (const float*)d_in[9];
  const float* fc1w  = (const float*)d_in[10];
  const float* fc1b  = (const float*)d_in[11];
  const float* fc2w  = (const float*)d_in[12];
  const float* fc2b  = (const float*)d_in[13];
  unsigned short* ws = (unsigned short*)d_ws;   // needs 96 KB
  float* out = (float*)d_out;

  prep_weights<<<dim3(96), dim3(64), 0, stream>>>(wq, wk, wvp, projw, fc1w, fc2w, ws);

  int nblk = in_sizes[0] / 4096;  // B = 4096 (T*C = 4096 elems per batch row)
  block_fused<<<dim3(nblk), dim3(256), 0, stream>>>(
      x, ln1w, ln1b, projb, ln2w, ln2b, fc1b, fc2b, ws, out);
}

// Round 2
// 103.742 us; speedup vs baseline: 1.3940x; 1.3940x over previous
//
#include <hip/hip_runtime.h>

typedef __attribute__((ext_vector_type(8))) short bf16x8;
typedef __attribute__((ext_vector_type(4))) float f32x4;
typedef __attribute__((ext_vector_type(2))) unsigned int u32x2;
typedef __attribute__((ext_vector_type(4))) unsigned int u32x4;

__device__ __forceinline__ unsigned short f2bf(float f) {
  return __builtin_bit_cast(unsigned short, (__bf16)f);
}
__device__ __forceinline__ unsigned pk2(float a, float b) {
  return (unsigned)f2bf(a) | ((unsigned)f2bf(b) << 16);
}
__device__ __forceinline__ float bf2f(unsigned short h) {
  unsigned u = ((unsigned)h) << 16;
  return __builtin_bit_cast(float, u);
}

#define MFMA16(a, b, c) __builtin_amdgcn_mfma_f32_16x16x32_bf16(a, b, c, 0, 0, 0)

#define LR  72     // 64-col tiles: 144 B/row, 4-bank rotate -> <=2-way conflict (free)
#define FFR 136    // 128-col FF1 half tile: 272 B/row
// regions (ushort offsets), aliased by liveness:
#define OFF_H   0        // H(LN1) -> P(exp scores) -> H2(LN2)
#define OFF_Q   4608     // Q -> FF1half (spans into K region)
#define OFF_K   9216     // K
#define OFF_VT  13824    // V^T -> x2
#define OFF_AT  18432    // attn row-major [t][d]
#define ZO      (OFF_AT + 64)   // 16B zero block in AT row-0 padding (cols 64..71)
#define LDS_TOT 23040    // 46,080 B -> 3 blocks/CU

// ---- weight prep: every chunk c (1 KB) holds frag[l*8+jj] = W[k][n],
//      k = 32*ks + 8*(l>>4) + jj,  n = 16*T + (l&15).
//   A-frag use: rows n of W^T.  B-frag use: B = W directly.
// chunks: [0,8)=WqT(x0.125) [8,16)=WkT [16,24)=WvT [24,32)=Wp [32,64)=W1T [64,96)=W2
__global__ void prep_weights(const float* __restrict__ wq, const float* __restrict__ wk,
                             const float* __restrict__ wv, const float* __restrict__ projw,
                             const float* __restrict__ fc1w, const float* __restrict__ fc2w,
                             unsigned short* __restrict__ ws) {
  int c = blockIdx.x, l = threadIdx.x;
  int g = l >> 4, jl = l & 15;
  int kind, T, ks;
  if (c < 8)       { kind = 0; T = c >> 1;        ks = c & 1; }
  else if (c < 16) { kind = 1; T = (c - 8) >> 1;  ks = (c - 8) & 1; }
  else if (c < 24) { kind = 2; T = (c - 16) >> 1; ks = (c - 16) & 1; }
  else if (c < 32) { kind = 3; T = (c - 24) >> 1; ks = (c - 24) & 1; }
  else if (c < 64) { kind = 4; T = (c - 32) >> 1; ks = (c - 32) & 1; }
  else             { kind = 5; T = (c - 64) >> 3; ks = (c - 64) & 7; }
  int n = 16 * T + jl;
  unsigned short* dst = ws + c * 512 + l * 8;
  #pragma unroll
  for (int jj = 0; jj < 8; ++jj) {
    int k = 32 * ks + 8 * g + jj;
    float v;
    if (kind == 0)      v = wq[(n >> 3) * 512 + k * 8 + (n & 7)] * 0.125f; // fold C^-0.5
    else if (kind == 1) v = wk[(n >> 3) * 512 + k * 8 + (n & 7)];
    else if (kind == 2) v = wv[(n >> 3) * 512 + k * 8 + (n & 7)];
    else if (kind == 3) v = projw[k * 64 + n];
    else if (kind == 4) v = fc1w[k * 256 + n];
    else                v = fc2w[k * 64 + n];
    dst[jj] = f2bf(v);
  }
}

__global__ __launch_bounds__(256) void block_fused(
    const float* __restrict__ x,
    const float* __restrict__ ln1w, const float* __restrict__ ln1b,
    const float* __restrict__ projb,
    const float* __restrict__ ln2w, const float* __restrict__ ln2b,
    const float* __restrict__ fc1b, const float* __restrict__ fc2b,
    const unsigned short* __restrict__ wsm, float* __restrict__ out) {
  __shared__ __attribute__((aligned(16))) unsigned short lds[LDS_TOT];

  const int tid  = threadIdx.x;
  const int w    = tid >> 6;     // wave 0..3 owns token rows 16w..16w+15
  const int lane = tid & 63;
  const int g    = lane >> 4;
  const int jl   = lane & 15;
  const size_t b = blockIdx.x;
  const float* xb = x + b * 4096;
  const f32x4 zf = {0.f, 0.f, 0.f, 0.f};

  const int myrow = 16 * w + jl;               // this lane's token row
  const int prow  = OFF_H  + myrow * LR;       // P row (aliases H)
  const int qrow  = OFF_Q  + myrow * LR;
  const int krow  = OFF_K  + myrow * LR;
  const int atrow = OFF_AT + myrow * LR;

  // ---------- LN1 (4 lanes per row; rows wave-private -> no barrier) ----------
  {
    int row = tid >> 2, q = tid & 3;
    const f32x4* xr = (const f32x4*)(xb + row * 64 + q * 16);
    f32x4 v0 = xr[0], v1 = xr[1], v2 = xr[2], v3 = xr[3];
    float s = 0.f, ss = 0.f;
    #pragma unroll
    for (int i = 0; i < 4; ++i) { s += v0[i] + v1[i] + v2[i] + v3[i];
      ss += v0[i]*v0[i] + v1[i]*v1[i] + v2[i]*v2[i] + v3[i]*v3[i]; }
    s  += __shfl_xor(s, 1, 64);  s  += __shfl_xor(s, 2, 64);
    ss += __shfl_xor(ss, 1, 64); ss += __shfl_xor(ss, 2, 64);
    float mean = s * 0.015625f;
    float rstd = rsqrtf(ss * 0.015625f - mean * mean + 1e-5f);
    const f32x4* wv4 = (const f32x4*)(ln1w + q * 16);
    const f32x4* bv4 = (const f32x4*)(ln1b + q * 16);
    f32x4 w0 = wv4[0], w1 = wv4[1], w2 = wv4[2], w3 = wv4[3];
    f32x4 b0 = bv4[0], b1 = bv4[1], b2 = bv4[2], b3 = bv4[3];
    f32x4 o0, o1, o2, o3;
    #pragma unroll
    for (int i = 0; i < 4; ++i) {
      o0[i] = (v0[i] - mean) * rstd * w0[i] + b0[i];
      o1[i] = (v1[i] - mean) * rstd * w1[i] + b1[i];
      o2[i] = (v2[i] - mean) * rstd * w2[i] + b2[i];
      o3[i] = (v3[i] - mean) * rstd * w3[i] + b3[i];
    }
    u32x4 lo = {pk2(o0[0],o0[1]), pk2(o0[2],o0[3]), pk2(o1[0],o1[1]), pk2(o1[2],o1[3])};
    u32x4 hi = {pk2(o2[0],o2[1]), pk2(o2[2],o2[3]), pk2(o3[0],o3[1]), pk2(o3[2],o3[3])};
    *(u32x4*)(lds + OFF_H + row * LR + q * 16)     = lo;
    *(u32x4*)(lds + OFF_H + row * LR + q * 16 + 8) = hi;
  }

  // ---------- QKV (swapped): D = W^T . H^T ; B-frag = own H row, read once ----------
  {
    bf16x8 hb0 = *(const bf16x8*)(lds + prow + 8 * g);
    bf16x8 hb1 = *(const bf16x8*)(lds + prow + 32 + 8 * g);
    #pragma unroll
    for (int t = 0; t < 3; ++t) {
      #pragma unroll
      for (int mt = 0; mt < 4; ++mt) {
        bf16x8 a0 = *(const bf16x8*)(wsm + (t * 8 + mt * 2 + 0) * 512 + lane * 8);
        bf16x8 a1 = *(const bf16x8*)(wsm + (t * 8 + mt * 2 + 1) * 512 + lane * 8);
        f32x4 acc = MFMA16(a0, hb0, zf);
        acc = MFMA16(a1, hb1, acc);
        if (t < 2) {   // Q/K row-major [t][n], packed
          u32x2 p = {pk2(acc[0], acc[1]), pk2(acc[2], acc[3])};
          *(u32x2*)(lds + (t == 0 ? qrow : krow) + 16 * mt + 4 * g) = p;
        } else {       // V^T row-major [n][t]
          #pragma unroll
          for (int r = 0; r < 4; ++r)
            lds[OFF_VT + (16 * mt + 4 * g + r) * LR + myrow] = f2bf(acc[r]);
        }
      }
    }
    if (tid == 0) *(u32x4*)(lds + ZO) = (u32x4){0u, 0u, 0u, 0u};
    // zero P tail (cols beyond causal reach; wave-private rows, H fully consumed)
    #pragma unroll
    for (int ct = 1; ct < 4; ++ct)
      if (ct > w) *(u32x2*)(lds + prow + 16 * ct + 4 * g) = (u32x2){0u, 0u};
  }
  __syncthreads();   // 1

  // ---------- attention: S^T = mfma(K,Q) -> lane-local softmax -> swapped PV ----------
  #pragma unroll
  for (int h = 0; h < 8; ++h) {
    int qoff = (g == 0) ? (qrow + h * 8) : ZO;
    bf16x8 bq = *(const bf16x8*)(lds + qoff);
    float sum = 0.f;
    for (int mi = 0; mi < w; ++mi) {            // full (unmasked) tiles only
      int koff = (g == 0) ? (OFF_K + (16 * mi + jl) * LR + h * 8) : ZO;
      bf16x8 ak = *(const bf16x8*)(lds + koff);
      f32x4 sc = MFMA16(ak, bq, zf);
      float e0 = __expf(sc[0]), e1 = __expf(sc[1]);
      float e2 = __expf(sc[2]), e3 = __expf(sc[3]);
      sum += (e0 + e1) + (e2 + e3);
      *(u32x2*)(lds + prow + 16 * mi + 4 * g) = (u32x2){pk2(e0, e1), pk2(e2, e3)};
    }
    {   // diagonal tile mi == w: mask s<=q  <=>  4g+r <= jl
      int koff = (g == 0) ? (krow + h * 8) : ZO;
      bf16x8 ak = *(const bf16x8*)(lds + koff);
      f32x4 sc = MFMA16(ak, bq, zf);
      float e0 = (4 * g + 0 <= jl) ? __expf(sc[0]) : 0.f;
      float e1 = (4 * g + 1 <= jl) ? __expf(sc[1]) : 0.f;
      float e2 = (4 * g + 2 <= jl) ? __expf(sc[2]) : 0.f;
      float e3 = (4 * g + 3 <= jl) ? __expf(sc[3]) : 0.f;
      sum += (e0 + e1) + (e2 + e3);
      *(u32x2*)(lds + prow + 16 * w + 4 * g) = (u32x2){pk2(e0, e1), pk2(e2, e3)};
    }
    sum += __shfl_xor(sum, 16, 64);
    sum += __shfl_xor(sum, 32, 64);
    float inv = __builtin_amdgcn_rcpf(sum);     // row sum of THIS lane's token row
    // PV swapped: attn^T = V^T . P^T  (A = V^T rows, B = P rows; K-dim = 64 full)
    f32x4 av = zf;
    #pragma unroll
    for (int ks = 0; ks < 2; ++ks) {
      int voff = (jl < 8) ? (OFF_VT + (h * 8 + jl) * LR + 32 * ks + 8 * g) : ZO;
      bf16x8 aV = *(const bf16x8*)(lds + voff);
      bf16x8 bP = *(const bf16x8*)(lds + prow + 32 * ks + 8 * g);
      av = MFMA16(aV, bP, av);
    }
    if (g < 2) {   // rows d = 4g+r valid (head dim 8); store attn ROW-major
      u32x2 o = {pk2(av[0] * inv, av[1] * inv), pk2(av[2] * inv, av[3] * inv)};
      *(u32x2*)(lds + atrow + h * 8 + 4 * g) = o;
    }
  }
  __syncthreads();   // 2

  // ---------- proj + residual: x2 = x + attn @ Wp + pb ----------
  {
    bf16x8 b0 = *(const bf16x8*)(wsm + (24 + w * 2 + 0) * 512 + lane * 8);
    bf16x8 b1 = *(const bf16x8*)(wsm + (24 + w * 2 + 1) * 512 + lane * 8);
    int j = myrow;
    float pb = projb[j];
    #pragma unroll
    for (int mi = 0; mi < 4; ++mi) {
      bf16x8 a0 = *(const bf16x8*)(lds + OFF_AT + (16 * mi + jl) * LR + 8 * g);
      bf16x8 a1 = *(const bf16x8*)(lds + OFF_AT + (16 * mi + jl) * LR + 32 + 8 * g);
      f32x4 acc = MFMA16(a0, b0, zf);
      acc = MFMA16(a1, b1, acc);
      #pragma unroll
      for (int r = 0; r < 4; ++r) {
        int i = 16 * mi + 4 * g + r;
        lds[OFF_VT + i * LR + j] = f2bf(xb[i * 64 + j] + acc[r] + pb);
      }
    }
  }
  __syncthreads();   // 3

  // ---------- LN2 (reads x2 bf16, writes H2; rows wave-private) ----------
  {
    int row = tid >> 2, q = tid & 3;
    u32x4 lo = *(const u32x4*)(lds + OFF_VT + row * LR + q * 16);
    u32x4 hi = *(const u32x4*)(lds + OFF_VT + row * LR + q * 16 + 8);
    float v[16];
    #pragma unroll
    for (int i = 0; i < 4; ++i) {
      v[2*i]    = bf2f((unsigned short)(lo[i] & 0xFFFF));
      v[2*i+1]  = bf2f((unsigned short)(lo[i] >> 16));
      v[8+2*i]  = bf2f((unsigned short)(hi[i] & 0xFFFF));
      v[8+2*i+1]= bf2f((unsigned short)(hi[i] >> 16));
    }
    float s = 0.f, ss = 0.f;
    #pragma unroll
    for (int i = 0; i < 16; ++i) { s += v[i]; ss += v[i] * v[i]; }
    s  += __shfl_xor(s, 1, 64);  s  += __shfl_xor(s, 2, 64);
    ss += __shfl_xor(ss, 1, 64); ss += __shfl_xor(ss, 2, 64);
    float mean = s * 0.015625f;
    float rstd = rsqrtf(ss * 0.015625f - mean * mean + 1e-5f);
    const f32x4* wv4 = (const f32x4*)(ln2w + q * 16);
    const f32x4* bv4 = (const f32x4*)(ln2b + q * 16);
    float o[16];
    #pragma unroll
    for (int i = 0; i < 16; ++i)
      o[i] = (v[i] - mean) * rstd * wv4[i >> 2][i & 3] + bv4[i >> 2][i & 3];
    u32x4 l2 = {pk2(o[0],o[1]), pk2(o[2],o[3]), pk2(o[4],o[5]), pk2(o[6],o[7])};
    u32x4 h2 = {pk2(o[8],o[9]), pk2(o[10],o[11]), pk2(o[12],o[13]), pk2(o[14],o[15])};
    *(u32x4*)(lds + OFF_H + row * LR + q * 16)     = l2;
    *(u32x4*)(lds + OFF_H + row * LR + q * 16 + 8) = h2;
  }
  // no barrier: H2 rows wave-private for fc1 B-frag

  // ---------- FF: fc1 swapped (FF1^T out -> row-major LDS), fc2 accumulates ----------
  f32x4 acc2[4];
  #pragma unroll
  for (int mi = 0; mi < 4; ++mi) acc2[mi] = zf;
  {
    bf16x8 hc0 = *(const bf16x8*)(lds + prow + 8 * g);       // H2 row (aliases P/H)
    bf16x8 hc1 = *(const bf16x8*)(lds + prow + 32 + 8 * g);
    #pragma unroll
    for (int half = 0; half < 2; ++half) {
      #pragma unroll
      for (int nt2 = 0; nt2 < 8; ++nt2) {
        int nt = half * 8 + nt2;
        bf16x8 a0 = *(const bf16x8*)(wsm + (32 + nt * 2 + 0) * 512 + lane * 8);
        bf16x8 a1 = *(const bf16x8*)(wsm + (32 + nt * 2 + 1) * 512 + lane * 8);
        f32x4 acc = MFMA16(a0, hc0, zf);
        acc = MFMA16(a1, hc1, acc);
        f32x4 bq = *(const f32x4*)(fc1b + 16 * nt + 4 * g);
        float r0 = fmaxf(acc[0] + bq[0], 0.f), r1 = fmaxf(acc[1] + bq[1], 0.f);
        float r2 = fmaxf(acc[2] + bq[2], 0.f), r3 = fmaxf(acc[3] + bq[3], 0.f);
        *(u32x2*)(lds + OFF_Q + myrow * FFR + 16 * nt2 + 4 * g) =
            (u32x2){pk2(r0, r1), pk2(r2, r3)};
      }
      __syncthreads();   // 4 / 6
      #pragma unroll
      for (int ksl = 0; ksl < 4; ++ksl) {
        bf16x8 b2 = *(const bf16x8*)(wsm + (64 + w * 8 + half * 4 + ksl) * 512 + lane * 8);
        #pragma unroll
        for (int mi = 0; mi < 4; ++mi) {
          bf16x8 a = *(const bf16x8*)(lds + OFF_Q + (16 * mi + jl) * FFR + 32 * ksl + 8 * g);
          acc2[mi] = MFMA16(a, b2, acc2[mi]);
        }
      }
      if (half == 0) __syncthreads();   // 5: protect FF1half overwrite
    }
  }

  // ---------- epilogue: out = x2 + ff ----------
  {
    int j = myrow;
    float fb = fc2b[j];
    float* ob = out + b * 4096;
    #pragma unroll
    for (int mi = 0; mi < 4; ++mi) {
      #pragma unroll
      for (int r = 0; r < 4; ++r) {
        int i = 16 * mi + 4 * g + r;
        ob[i * 64 + j] = bf2f(lds[OFF_VT + i * LR + j]) + acc2[mi][r] + fb;
      }
    }
  }
}

extern "C" void kernel_launch(void* const* d_in, const int* in_sizes, int n_in,
                              void* d_out, int out_size, void* d_ws, size_t ws_size,
                              hipStream_t stream) {
  const float* x     = (const float*)d_in[0];
  const float* ln1w  = (const float*)d_in[1];
  const float* ln1b  = (const float*)d_in[2];
  const float* wq    = (const float*)d_in[3];
  const float* wk    = (const float*)d_in[4];
  const float* wvp   = (const float*)d_in[5];
  const float* projw = (const float*)d_in[6];
  const float* projb = (const float*)d_in[7];
  const float* ln2w  = (const float*)d_in[8];
  const float* ln2b  = (const float*)d_in[9];
  const float* fc1w  = (const float*)d_in[10];
  const float* fc1b  = (const float*)d_in[11];
  const float* fc2w  = (const float*)d_in[12];
  const float* fc2b  = (const float*)d_in[13];
  unsigned short* ws = (unsigned short*)d_ws;   // 96 KB of repacked weights
  float* out = (float*)d_out;

  prep_weights<<<dim3(96), dim3(64), 0, stream>>>(wq, wk, wvp, projw, fc1w, fc2w, ws);

  int nblk = in_sizes[0] / 4096;
  block_fused<<<dim3(nblk), dim3(256), 0, stream>>>(
      x, ln1w, ln1b, projb, ln2w, ln2b, fc1b, fc2b, ws, out);
}